// Round 14
// baseline (667.705 us; speedup 1.0000x reference)
//
#include <hip/hip_runtime.h>

#define TSEQ 512
#define NTH  256    // 4 waves: 0,1 layer0; 2,3 layer1 (skew 2)
#define BT   8      // 512 blocks -> 2 blocks/CU; each SIMD: 1 wave from EACH block
// R14: independent barrier domains. Each wave owns 32 units (2 row-tiles T=0,1);
// MFMA cols 8-15 duplicate batch 0-7. Activations NOT duplicated: lanes rl<8
// activate tile0, rl>=8 activate tile1 (their dup-batch accs are identical).
// Per-CU VALU/trans unchanged vs R13; MFMA x2 (pipe was 26% busy); 2 blocks'
// barriers interleave on every SIMD.

typedef __attribute__((ext_vector_type(8))) _Float16 half8;
typedef __attribute__((ext_vector_type(4))) float f32x4;
typedef __attribute__((ext_vector_type(4))) unsigned int u32x4;

__device__ __forceinline__ unsigned packF16x2(float a, float b) {
    _Float16 ha = (_Float16)a, hb = (_Float16)b;
    unsigned short ua = __builtin_bit_cast(unsigned short, ha);
    unsigned short ub = __builtin_bit_cast(unsigned short, hb);
    return (unsigned)ua | ((unsigned)ub << 16);
}
__device__ __forceinline__ half8 packA16s(const float w8[8], float s) {
    u32x4 W = { packF16x2(w8[0]*s, w8[1]*s), packF16x2(w8[2]*s, w8[3]*s),
                packF16x2(w8[4]*s, w8[5]*s), packF16x2(w8[6]*s, w8[7]*s) };
    return __builtin_bit_cast(half8, W);
}

#define MFMA(a, b, c) __builtin_amdgcn_mfma_f32_16x16x32_f16((a), (b), (c), 0, 0, 0)
#define LD128H(p) __builtin_bit_cast(half8, *(const u32x4*)(p))

// fused LSTM unit update with PRE-SCALED pre-acts (scales folded into W/b):
// ai,af,ao = -log2e * preact;  ag = 2*log2e * preact
__device__ __forceinline__ float act_fused(float ai, float af, float ag, float ao, float* c) {
    const float L2E2 = 2.88539008177792681472f;
    float ei = __builtin_amdgcn_exp2f(ai);
    float ef = __builtin_amdgcn_exp2f(af);
    float eg = __builtin_amdgcn_exp2f(ag);
    float eo = __builtin_amdgcn_exp2f(ao);
    float sf = __builtin_amdgcn_rcpf(1.0f + ef);
    float ig = (eg - 1.0f) * __builtin_amdgcn_rcpf((1.0f + ei) * (eg + 1.0f));
    float cn = fmaf(*c, sf, ig);
    *c = cn;
    float ec = __builtin_amdgcn_exp2f(cn * L2E2);
    return (ec - 1.0f) * __builtin_amdgcn_rcpf((1.0f + eo) * (ec + 1.0f));
}

__global__ __launch_bounds__(NTH, 1)
void lstm2_mfma(const float* __restrict__ x,
                const float* __restrict__ W_ih0, const float* __restrict__ W_hh0,
                const float* __restrict__ b_ih0, const float* __restrict__ b_hh0,
                const float* __restrict__ W_ih1, const float* __restrict__ W_hh1,
                const float* __restrict__ b_ih1, const float* __restrict__ b_hh1,
                const float* __restrict__ W_fc,  const float* __restrict__ b_fc,
                float* __restrict__ out)
{
    const int tid  = threadIdx.x;
    const int lane = tid & 63;
    const int wv   = tid >> 6;        // 0,1: layer0; 2,3: layer1
    const int rl   = lane & 15;       // MFMA row/col index
    const int g    = lane >> 4;       // k-group 0..3
    const int n    = rl & 7;          // batch col (cols 8-15 duplicate)
    const int T    = rl >> 3;         // row-tile this lane activates/writes
    const int b0   = blockIdx.x * BT;
    const int w    = wv & 1;          // unit-half: units [32w, 32w+32)

    const float NL2E  = -1.44269504088896340736f;
    const float PL2E2 =  2.88539008177792681472f;

    // f16 h planes: [8 batch rows x 32 words], depth-2 ping-pong.
    // h[t] at parity (t+1)&1. Reads use n=rl&7 (cols 8-15 self-duplicate).
    __shared__ unsigned h0P0[256], h0P1[256];
    __shared__ unsigned h1P0[256], h1P1[256];
    __shared__ float fcl[64 * 9];     // [unit][batch], padded 8->9

    for (int i2 = tid; i2 < 256; i2 += NTH) {
        h0P0[i2] = 0u; h0P1[i2] = 0u; h1P0[i2] = 0u; h1P1[i2] = 0u;
    }
    __syncthreads();

    // diagonal-swizzle offsets (loop-invariant)
    const int offL = n*32 + (((g + n) & 7) << 2);           // b128 read, k-half 0
    const int offH = n*32 + (((4 + g + n) & 7) << 2);       // b128 read, k-half 1
    const int q0w  = 16*w + 8*T + 2*g;                      // this lane's write words
    const int woff = n*32 + ((((q0w >> 2) + n) & 7) << 2) + (q0w & 3);

    if (wv < 2) {
        // ======== LAYER 0: wave w owns units [32w,32w+32) = 2 row-tiles ========
        half8 A0[4][2][2];   // [gate][k-half][tile]
        half8 Ax[4][2];      // x-term [gate][tile]: k0-3 = W_ih0 row (g==0), else 0
        f32x4 bias4[4][2];   // [gate][tile]
        #pragma unroll
        for (int G = 0; G < 4; ++G) {
            const float sc = (G == 2) ? PL2E2 : NL2E;
            #pragma unroll
            for (int Tt = 0; Tt < 2; ++Tt) {
                const int row = 64*G + 32*w + 16*Tt + rl;
                #pragma unroll
                for (int s = 0; s < 2; ++s) {
                    float w8[8];
                    const float* src = W_hh0 + row*64 + s*32 + g*8;
                    #pragma unroll
                    for (int e = 0; e < 8; ++e) w8[e] = src[e];
                    A0[G][s][Tt] = packA16s(w8, sc);
                }
                u32x4 ax = {0u, 0u, 0u, 0u};
                if (g == 0) {
                    ax.x = packF16x2(W_ih0[row*4+0]*sc, W_ih0[row*4+1]*sc);
                    ax.y = packF16x2(W_ih0[row*4+2]*sc, W_ih0[row*4+3]*sc);
                }
                Ax[G][Tt] = __builtin_bit_cast(half8, ax);
                const int rb = 64*G + 32*w + 16*Tt + 4*g;
                bias4[G][Tt].x = (b_ih0[rb+0] + b_hh0[rb+0]) * sc;
                bias4[G][Tt].y = (b_ih0[rb+1] + b_hh0[rb+1]) * sc;
                bias4[G][Tt].z = (b_ih0[rb+2] + b_hh0[rb+2]) * sc;
                bias4[G][Tt].w = (b_ih0[rb+3] + b_hh0[rb+3]) * sc;
            }
        }
        float cst[4] = {0.f, 0.f, 0.f, 0.f};

        // prologue: x[0] load + pre-pack
        f32x4 xf = *(const f32x4*)(x + ((size_t)(b0 + n) * TSEQ) * 4);
        unsigned bx0 = packF16x2(xf.x, xf.y);
        unsigned bx1 = packF16x2(xf.z, xf.w);

        auto body0 = [&](const unsigned* rP, unsigned* wP, int i) {
            if (i + 1 < TSEQ)
                xf = *(const f32x4*)(x + ((size_t)(b0 + n) * TSEQ + (i + 1)) * 4);

            half8 B0 = LD128H(rP + offL);
            half8 B1 = LD128H(rP + offH);
            u32x4 tx = {0u, 0u, 0u, 0u};
            if (g == 0) { tx.x = bx0; tx.y = bx1; }
            half8 Bx = __builtin_bit_cast(half8, tx);

            f32x4 acc[2][4];
            __builtin_amdgcn_s_setprio(1);
            #pragma unroll
            for (int G = 0; G < 4; ++G) acc[0][G] = MFMA(Ax[G][0], Bx, bias4[G][0]);
            #pragma unroll
            for (int G = 0; G < 4; ++G) acc[1][G] = MFMA(Ax[G][1], Bx, bias4[G][1]);
            #pragma unroll
            for (int G = 0; G < 4; ++G) acc[0][G] = MFMA(A0[G][0][0], B0, acc[0][G]);
            #pragma unroll
            for (int G = 0; G < 4; ++G) acc[1][G] = MFMA(A0[G][0][1], B0, acc[1][G]);
            #pragma unroll
            for (int G = 0; G < 4; ++G) acc[0][G] = MFMA(A0[G][1][0], B1, acc[0][G]);
            #pragma unroll
            for (int G = 0; G < 4; ++G) acc[1][G] = MFMA(A0[G][1][1], B1, acc[1][G]);
            __builtin_amdgcn_s_setprio(0);

            // lane activates only its tile T (other tile's acc is the dup lane's job)
            f32x4 s0 = T ? acc[1][0] : acc[0][0];
            f32x4 s1 = T ? acc[1][1] : acc[0][1];
            f32x4 s2 = T ? acc[1][2] : acc[0][2];
            f32x4 s3 = T ? acc[1][3] : acc[0][3];
            float hv[4];
            #pragma unroll
            for (int j = 0; j < 4; ++j)
                hv[j] = act_fused(s0[j], s1[j], s2[j], s3[j], &cst[j]);

            bx0 = packF16x2(xf.x, xf.y);
            bx1 = packF16x2(xf.z, xf.w);

            *(uint2*)(wP + woff) = make_uint2(packF16x2(hv[0], hv[1]),
                                              packF16x2(hv[2], hv[3]));
        };

        for (int ii = 0; ii < 256; ++ii) {
            body0(h0P0, h0P1, 2*ii);     __syncthreads();  // i=2ii   (p=0)
            body0(h0P1, h0P0, 2*ii + 1); __syncthreads();  // i=2ii+1 (p=1)
        }
        __syncthreads();   // i=512 slot (L1 tail)
        __syncthreads();   // i=513 slot (L1 tail)
    } else {
        // ======== LAYER 1 (skew 2): iter i computes t=i-2; h0 frags prefetched at i-1 ====
        half8 A1[4][4][2];   // [gate][s][tile]: s=0,1 W_ih1 (vs h0); s=2,3 W_hh1 (vs h1)
        f32x4 bias4[4][2];
        #pragma unroll
        for (int G = 0; G < 4; ++G) {
            const float sc = (G == 2) ? PL2E2 : NL2E;
            #pragma unroll
            for (int Tt = 0; Tt < 2; ++Tt) {
                const int row = 64*G + 32*w + 16*Tt + rl;
                #pragma unroll
                for (int s = 0; s < 4; ++s) {
                    float w8[8];
                    const float* src = (s < 2) ? (W_ih1 + row*64 + s*32 + g*8)
                                               : (W_hh1 + row*64 + (s-2)*32 + g*8);
                    #pragma unroll
                    for (int e = 0; e < 8; ++e) w8[e] = src[e];
                    A1[G][s][Tt] = packA16s(w8, sc);
                }
                const int rb = 64*G + 32*w + 16*Tt + 4*g;
                bias4[G][Tt].x = (b_ih1[rb+0] + b_hh1[rb+0]) * sc;
                bias4[G][Tt].y = (b_ih1[rb+1] + b_hh1[rb+1]) * sc;
                bias4[G][Tt].z = (b_ih1[rb+2] + b_hh1[rb+2]) * sc;
                bias4[G][Tt].w = (b_ih1[rb+3] + b_hh1[rb+3]) * sc;
            }
        }
        float cst[4] = {0.f, 0.f, 0.f, 0.f};
        const int u0 = 32*w + 16*T + 4*g;

        half8 pB0 = {}, pB1 = {};   // prefetched h0[t] frags

        auto body1 = [&](const unsigned* r1P, unsigned* wP,
                         const unsigned* n0P, bool wrFC) {
            half8 B2 = LD128H(r1P + offL);
            half8 B3 = LD128H(r1P + offH);

            f32x4 acc[2][4];
            __builtin_amdgcn_s_setprio(1);
            #pragma unroll
            for (int G = 0; G < 4; ++G) acc[0][G] = MFMA(A1[G][0][0], pB0, bias4[G][0]);
            #pragma unroll
            for (int G = 0; G < 4; ++G) acc[1][G] = MFMA(A1[G][0][1], pB0, bias4[G][1]);
            #pragma unroll
            for (int G = 0; G < 4; ++G) acc[0][G] = MFMA(A1[G][1][0], pB1, acc[0][G]);
            #pragma unroll
            for (int G = 0; G < 4; ++G) acc[1][G] = MFMA(A1[G][1][1], pB1, acc[1][G]);
            #pragma unroll
            for (int G = 0; G < 4; ++G) acc[0][G] = MFMA(A1[G][2][0], B2, acc[0][G]);
            #pragma unroll
            for (int G = 0; G < 4; ++G) acc[1][G] = MFMA(A1[G][2][1], B2, acc[1][G]);
            #pragma unroll
            for (int G = 0; G < 4; ++G) acc[0][G] = MFMA(A1[G][3][0], B3, acc[0][G]);
            #pragma unroll
            for (int G = 0; G < 4; ++G) acc[1][G] = MFMA(A1[G][3][1], B3, acc[1][G]);
            __builtin_amdgcn_s_setprio(0);

            // prefetch h0[t+1] now: latency hides under act+pack+write
            pB0 = LD128H(n0P + offL);
            pB1 = LD128H(n0P + offH);

            f32x4 s0 = T ? acc[1][0] : acc[0][0];
            f32x4 s1 = T ? acc[1][1] : acc[0][1];
            f32x4 s2 = T ? acc[1][2] : acc[0][2];
            f32x4 s3 = T ? acc[1][3] : acc[0][3];
            float hv[4];
            #pragma unroll
            for (int j = 0; j < 4; ++j)
                hv[j] = act_fused(s0[j], s1[j], s2[j], s3[j], &cst[j]);
            *(uint2*)(wP + woff) = make_uint2(packF16x2(hv[0], hv[1]),
                                              packF16x2(hv[2], hv[3]));
            if (wrFC) {
                #pragma unroll
                for (int j = 0; j < 4; ++j) fcl[(u0 + j)*9 + n] = hv[j];
            }
        };

        __syncthreads();                         // i=0 (idle)
        // i=1: prefetch-only — h0[0] lives at parity 1
        pB0 = LD128H(h0P1 + offL);
        pB1 = LD128H(h0P1 + offH);
        __syncthreads();                         // i=1
        for (int ii = 0; ii < 256; ++ii) {
            body1(h1P0, h1P1, h0P0, false);     __syncthreads();  // i=2+2ii (p=0)
            body1(h1P1, h1P0, h0P1, ii == 255); __syncthreads();  // i=3+2ii (p=1)
        }
    }

    // ---- FC: out[b] = h1_last[b,:] . W_fc + b_fc ----
    if (tid < BT) {
        float acc = b_fc[0];
        #pragma unroll 16
        for (int u = 0; u < 64; ++u) acc += fcl[u*9 + tid] * W_fc[u];
        out[b0 + tid] = acc;
    }
}

extern "C" void kernel_launch(void* const* d_in, const int* in_sizes, int n_in,
                              void* d_out, int out_size, void* d_ws, size_t ws_size,
                              hipStream_t stream) {
    const float* x     = (const float*)d_in[0];
    const float* W_ih0 = (const float*)d_in[1];
    const float* W_hh0 = (const float*)d_in[2];
    const float* b_ih0 = (const float*)d_in[3];
    const float* b_hh0 = (const float*)d_in[4];
    const float* W_ih1 = (const float*)d_in[5];
    const float* W_hh1 = (const float*)d_in[6];
    const float* b_ih1 = (const float*)d_in[7];
    const float* b_hh1 = (const float*)d_in[8];
    const float* W_fc  = (const float*)d_in[9];
    const float* b_fc  = (const float*)d_in[10];
    float* out = (float*)d_out;

    dim3 grid(4096 / BT), block(NTH);
    hipLaunchKernelGGL(lstm2_mfma, grid, block, 0, stream,
                       x, W_ih0, W_hh0, b_ih0, b_hh0,
                       W_ih1, W_hh1, b_ih1, b_hh1, W_fc, b_fc, out);
}

// Round 15
// 363.215 us; speedup vs baseline: 1.8383x; 1.8383x over previous
//
#include <hip/hip_runtime.h>

#define TSEQ 512
#define NTH  512    // 8 waves: 0-3 layer0, 4-7 layer1; 16 batch/block, 256 blocks = 1/CU
// R15 (from best=R13): ANTI-PHASE two-phase schedule. Per iter i:
//   ph1: L0 ds_read+MFMA(step i)      || L1 act+write h1[i-2], prefetch h0[i-1]
//   barrier1
//   ph2: L0 act+write h0[i]           || L1 ds_read h1[i-2]+MFMA(step i-1)
//   barrier2
// Each SIMD hosts one L0 + one L1 wave (waves 0..7 -> SIMD 0..3,0..3): the
// MFMA cluster of one overlaps the trans-heavy act of the other (m114).
// No preact round-trip (each layer keeps its own act). h1 needs ONE plane.

typedef __attribute__((ext_vector_type(8))) _Float16 half8;
typedef __attribute__((ext_vector_type(4))) float f32x4;
typedef __attribute__((ext_vector_type(4))) unsigned int u32x4;

__device__ __forceinline__ unsigned packF16x2(float a, float b) {
    _Float16 ha = (_Float16)a, hb = (_Float16)b;
    unsigned short ua = __builtin_bit_cast(unsigned short, ha);
    unsigned short ub = __builtin_bit_cast(unsigned short, hb);
    return (unsigned)ua | ((unsigned)ub << 16);
}
__device__ __forceinline__ half8 packA16s(const float w8[8], float s) {
    u32x4 W = { packF16x2(w8[0]*s, w8[1]*s), packF16x2(w8[2]*s, w8[3]*s),
                packF16x2(w8[4]*s, w8[5]*s), packF16x2(w8[6]*s, w8[7]*s) };
    return __builtin_bit_cast(half8, W);
}

#define MFMA(a, b, c) __builtin_amdgcn_mfma_f32_16x16x32_f16((a), (b), (c), 0, 0, 0)
#define LD128H(p) __builtin_bit_cast(half8, *(const u32x4*)(p))

// fused LSTM unit update with PRE-SCALED pre-acts (scales folded into W/b):
// ai,af,ao = -log2e * preact;  ag = 2*log2e * preact
__device__ __forceinline__ float act_fused(float ai, float af, float ag, float ao, float* c) {
    const float L2E2 = 2.88539008177792681472f;
    float ei = __builtin_amdgcn_exp2f(ai);
    float ef = __builtin_amdgcn_exp2f(af);
    float eg = __builtin_amdgcn_exp2f(ag);
    float eo = __builtin_amdgcn_exp2f(ao);
    float sf = __builtin_amdgcn_rcpf(1.0f + ef);
    float ig = (eg - 1.0f) * __builtin_amdgcn_rcpf((1.0f + ei) * (eg + 1.0f));
    float cn = fmaf(*c, sf, ig);
    *c = cn;
    float ec = __builtin_amdgcn_exp2f(cn * L2E2);
    return (ec - 1.0f) * __builtin_amdgcn_rcpf((1.0f + eo) * (ec + 1.0f));
}

__global__ __launch_bounds__(NTH, 1)
void lstm2_mfma(const float* __restrict__ x,
                const float* __restrict__ W_ih0, const float* __restrict__ W_hh0,
                const float* __restrict__ b_ih0, const float* __restrict__ b_hh0,
                const float* __restrict__ W_ih1, const float* __restrict__ W_hh1,
                const float* __restrict__ b_ih1, const float* __restrict__ b_hh1,
                const float* __restrict__ W_fc,  const float* __restrict__ b_fc,
                float* __restrict__ out)
{
    const int tid  = threadIdx.x;
    const int lane = tid & 63;
    const int wv   = tid >> 6;        // 0-3: layer0, 4-7: layer1
    const int rl   = lane & 15;       // MFMA row/col index = batch col n
    const int g    = lane >> 4;       // k-group 0..3
    const int b0   = blockIdx.x * 16;

    const float NL2E  = -1.44269504088896340736f;
    const float PL2E2 =  2.88539008177792681472f;

    // h0: f16 planes, depth-2 ping-pong (h0[t] at parity (t+1)&1).
    // h1: SINGLE plane (write ph1 / read ph2, barrier1 between; value dead after).
    __shared__ unsigned h0P0[512], h0P1[512];
    __shared__ unsigned h1P[512];
    __shared__ float fcl[64 * 17];    // padded 16->17

    for (int i2 = tid; i2 < 512; i2 += NTH) {
        h0P0[i2] = 0u; h0P1[i2] = 0u; h1P[i2] = 0u;
    }
    __syncthreads();

    // diagonal-swizzle b128 read offsets (loop-invariant)
    const int offL = rl*32 + (((g + rl) & 7) << 2);         // k-half 0
    const int offH = rl*32 + (((4 + g + rl) & 7) << 2);     // k-half 1
    const int q0w  = 8*((wv & 3)) + 2*g;
    const int woff = rl*32 + ((((q0w >> 2) + rl) & 7) << 2) + (q0w & 3);

    if (wv < 4) {
        // ======== LAYER 0: wave w owns units [16w,16w+16) for all 4 gates ========
        const int w = wv;
        half8 A0[4][2];   // [gate][k-half of W_hh0]
        half8 Ax[4];      // x-term: k0-3 = W_ih0 row (g==0 lanes), else 0
        f32x4 bias4[4];
        #pragma unroll
        for (int G = 0; G < 4; ++G) {
            const float sc = (G == 2) ? PL2E2 : NL2E;
            const int row = 64*G + 16*w + rl;
            #pragma unroll
            for (int s = 0; s < 2; ++s) {
                float w8[8];
                const float* src = W_hh0 + row*64 + s*32 + g*8;
                #pragma unroll
                for (int e = 0; e < 8; ++e) w8[e] = src[e];
                A0[G][s] = packA16s(w8, sc);
            }
            {
                u32x4 ax = {0u, 0u, 0u, 0u};
                if (g == 0) {
                    ax.x = packF16x2(W_ih0[row*4+0]*sc, W_ih0[row*4+1]*sc);
                    ax.y = packF16x2(W_ih0[row*4+2]*sc, W_ih0[row*4+3]*sc);
                }
                Ax[G] = __builtin_bit_cast(half8, ax);
            }
            const int rb = 64*G + 16*w + 4*g;
            bias4[G].x = (b_ih0[rb+0] + b_hh0[rb+0]) * sc;
            bias4[G].y = (b_ih0[rb+1] + b_hh0[rb+1]) * sc;
            bias4[G].z = (b_ih0[rb+2] + b_hh0[rb+2]) * sc;
            bias4[G].w = (b_ih0[rb+3] + b_hh0[rb+3]) * sc;
        }
        float cst[4] = {0.f, 0.f, 0.f, 0.f};
        f32x4 acc[4];                 // lives across barrier1 (ph1 -> ph2)

        // prologue: x[0] load + pre-pack
        f32x4 xf = *(const f32x4*)(x + ((size_t)(b0 + rl) * TSEQ) * 4);
        unsigned bx0 = packF16x2(xf.x, xf.y);
        unsigned bx1 = packF16x2(xf.z, xf.w);

        auto ph1 = [&](const unsigned* rP, int i) {   // rP = h0[i-1] plane (parity i&1)
            if (i + 1 < TSEQ)
                xf = *(const f32x4*)(x + ((size_t)(b0 + rl) * TSEQ + (i + 1)) * 4);
            half8 B0 = LD128H(rP + offL);
            half8 B1 = LD128H(rP + offH);
            u32x4 tx = {0u, 0u, 0u, 0u};
            if (g == 0) { tx.x = bx0; tx.y = bx1; }
            half8 Bx = __builtin_bit_cast(half8, tx);
            __builtin_amdgcn_s_setprio(1);
            #pragma unroll
            for (int G = 0; G < 4; ++G) acc[G] = MFMA(Ax[G], Bx, bias4[G]);
            #pragma unroll
            for (int G = 0; G < 4; ++G) acc[G] = MFMA(A0[G][0], B0, acc[G]);
            #pragma unroll
            for (int G = 0; G < 4; ++G) acc[G] = MFMA(A0[G][1], B1, acc[G]);
            __builtin_amdgcn_s_setprio(0);
        };
        auto ph2 = [&](unsigned* wP) {                // wP = h0[i] plane (parity (i+1)&1)
            float hv[4];
            #pragma unroll
            for (int j = 0; j < 4; ++j)
                hv[j] = act_fused(acc[0][j], acc[1][j], acc[2][j], acc[3][j], &cst[j]);
            bx0 = packF16x2(xf.x, xf.y);
            bx1 = packF16x2(xf.z, xf.w);
            *(uint2*)(wP + woff) = make_uint2(packF16x2(hv[0], hv[1]),
                                              packF16x2(hv[2], hv[3]));
        };

        for (int ii = 0; ii <= 256; ++ii) {
            const int i0 = 2*ii, i1 = 2*ii + 1;
            if (i0 < TSEQ) ph1(h0P0, i0);
            __syncthreads();                          // barrier1
            if (i0 < TSEQ) ph2(h0P1);
            __syncthreads();                          // barrier2
            if (i1 < TSEQ) ph1(h0P1, i1);
            __syncthreads();                          // barrier1
            if (i1 < TSEQ) ph2(h0P0);
            __syncthreads();                          // barrier2
        }
    } else {
        // ======== LAYER 1: ph2 of iter i computes step t=i-1; act lands in ph1 of i+1 ====
        const int w = wv - 4;
        half8 A1[4][4];   // s=0,1: W_ih1 (vs h0); s=2,3: W_hh1 (vs h1)
        f32x4 bias4[4];
        #pragma unroll
        for (int G = 0; G < 4; ++G) {
            const float sc = (G == 2) ? PL2E2 : NL2E;
            const int row = 64*G + 16*w + rl;
            #pragma unroll
            for (int s = 0; s < 4; ++s) {
                float w8[8];
                const float* src = (s < 2) ? (W_ih1 + row*64 + s*32 + g*8)
                                           : (W_hh1 + row*64 + (s-2)*32 + g*8);
                #pragma unroll
                for (int e = 0; e < 8; ++e) w8[e] = src[e];
                A1[G][s] = packA16s(w8, sc);
            }
            const int rb = 64*G + 16*w + 4*g;
            bias4[G].x = (b_ih1[rb+0] + b_hh1[rb+0]) * sc;
            bias4[G].y = (b_ih1[rb+1] + b_hh1[rb+1]) * sc;
            bias4[G].z = (b_ih1[rb+2] + b_hh1[rb+2]) * sc;
            bias4[G].w = (b_ih1[rb+3] + b_hh1[rb+3]) * sc;
        }
        float cst[4] = {0.f, 0.f, 0.f, 0.f};
        const int u0 = 16*w + 4*g;
        f32x4 acc[4];                 // lives across barrier2 (ph2 -> next ph1)
        half8 pB0 = {}, pB1 = {};     // h0[i-1] frags, prefetched in ph1

        auto ph1 = [&](const unsigned* n0P, int i) {  // n0P = h0[i-1] plane (parity i&1)
            if (i >= 2) {                             // act for step t=i-2
                float hv[4];
                #pragma unroll
                for (int j = 0; j < 4; ++j)
                    hv[j] = act_fused(acc[0][j], acc[1][j], acc[2][j], acc[3][j], &cst[j]);
                *(uint2*)(h1P + woff) = make_uint2(packF16x2(hv[0], hv[1]),
                                                   packF16x2(hv[2], hv[3]));
                if (i == TSEQ + 1) {                  // hv = h1[511]
                    #pragma unroll
                    for (int j = 0; j < 4; ++j) fcl[(u0 + j)*17 + rl] = hv[j];
                }
            }
            if (i >= 1 && i <= TSEQ) {                // prefetch h0[i-1] frags
                pB0 = LD128H(n0P + offL);
                pB1 = LD128H(n0P + offH);
            }
        };
        auto ph2 = [&](int i) {                       // MFMA for step t=i-1
            if (i >= 1 && i <= TSEQ) {
                half8 B2 = LD128H(h1P + offL);        // h1[i-2], written in ph1
                half8 B3 = LD128H(h1P + offH);
                __builtin_amdgcn_s_setprio(1);
                #pragma unroll
                for (int G = 0; G < 4; ++G) acc[G] = MFMA(A1[G][0], pB0, bias4[G]);
                #pragma unroll
                for (int G = 0; G < 4; ++G) acc[G] = MFMA(A1[G][1], pB1, acc[G]);
                #pragma unroll
                for (int G = 0; G < 4; ++G) acc[G] = MFMA(A1[G][2], B2, acc[G]);
                #pragma unroll
                for (int G = 0; G < 4; ++G) acc[G] = MFMA(A1[G][3], B3, acc[G]);
                __builtin_amdgcn_s_setprio(0);
            }
        };

        for (int ii = 0; ii <= 256; ++ii) {
            const int i0 = 2*ii, i1 = 2*ii + 1;
            ph1(h0P0, i0);
            __syncthreads();                          // barrier1
            ph2(i0);
            __syncthreads();                          // barrier2
            ph1(h0P1, i1);
            __syncthreads();                          // barrier1
            ph2(i1);
            __syncthreads();                          // barrier2
        }
    }

    // ---- FC: out[b] = h1_last[b,:] . W_fc + b_fc ----
    if (tid < 16) {
        float acc = b_fc[0];
        #pragma unroll 16
        for (int u = 0; u < 64; ++u) acc += fcl[u*17 + tid] * W_fc[u];
        out[b0 + tid] = acc;
    }
}

extern "C" void kernel_launch(void* const* d_in, const int* in_sizes, int n_in,
                              void* d_out, int out_size, void* d_ws, size_t ws_size,
                              hipStream_t stream) {
    const float* x     = (const float*)d_in[0];
    const float* W_ih0 = (const float*)d_in[1];
    const float* W_hh0 = (const float*)d_in[2];
    const float* b_ih0 = (const float*)d_in[3];
    const float* b_hh0 = (const float*)d_in[4];
    const float* W_ih1 = (const float*)d_in[5];
    const float* W_hh1 = (const float*)d_in[6];
    const float* b_ih1 = (const float*)d_in[7];
    const float* b_hh1 = (const float*)d_in[8];
    const float* W_fc  = (const float*)d_in[9];
    const float* b_fc  = (const float*)d_in[10];
    float* out = (float*)d_out;

    dim3 grid(4096 / 16), block(NTH);
    hipLaunchKernelGGL(lstm2_mfma, grid, block, 0, stream,
                       x, W_ih0, W_hh0, b_ih0, b_hh0,
                       W_ih1, W_hh1, b_ih1, b_hh1, W_fc, b_fc, out);
}